// Round 12
// baseline (313.566 us; speedup 1.0000x reference)
//
#include <hip/hip_runtime.h>
#include <stdint.h>

typedef unsigned short u16;
typedef unsigned int u32;
typedef __bf16 bf16x8 __attribute__((ext_vector_type(8)));
typedef float f32x4 __attribute__((ext_vector_type(4)));

// ---------- small helpers ----------
__device__ __forceinline__ u16 f2b(float f) {
  uint32_t u = __float_as_uint(f);
  u += 0x7FFFu + ((u >> 16) & 1u);   // RNE (inputs are finite/normal)
  return (u16)(u >> 16);
}
__device__ __forceinline__ float b2f(u16 u) {
  return __uint_as_float(((uint32_t)u) << 16);
}
__device__ __forceinline__ float b2f_lo(u32 w) {  // low bf16 of a dword
  return __uint_as_float(w << 16);
}
__device__ __forceinline__ float b2f_hi(u32 w) {  // high bf16 of a dword
  return __uint_as_float(w & 0xffff0000u);
}

// ---------- convert fp32 -> bf16, vectorized ----------
__global__ __launch_bounds__(256) void cvt_kernel(const float* __restrict__ s,
                                                  u16* __restrict__ d, int n4) {
  int i = blockIdx.x * 256 + threadIdx.x;
  if (i >= n4) return;
  float4 v = reinterpret_cast<const float4*>(s)[i];
  ushort4 o;
  o.x = f2b(v.x); o.y = f2b(v.y); o.z = f2b(v.z); o.w = f2b(v.w);
  reinterpret_cast<ushort4*>(d)[i] = o;
}

// ---------- transpose 4x (1024x1024 fp32 -> bf16 [N][K]), z selects matrix ----------
__global__ __launch_bounds__(256) void transpose4_kernel(
    const float* __restrict__ s0, const float* __restrict__ s1,
    const float* __restrict__ s2, const float* __restrict__ s3,
    u16* __restrict__ d0, u16* __restrict__ d1,
    u16* __restrict__ d2, u16* __restrict__ d3) {
  const int z = blockIdx.z;
  const float* s = z == 0 ? s0 : (z == 1 ? s1 : (z == 2 ? s2 : s3));
  u16*        d = z == 0 ? d0 : (z == 1 ? d1 : (z == 2 ? d2 : d3));
  __shared__ float tile[32][33];
  const int tx = threadIdx.x, ty = threadIdx.y;          // (32, 8)
  const int bx = blockIdx.x * 32, by = blockIdx.y * 32;
#pragma unroll
  for (int j = 0; j < 32; j += 8)
    tile[ty + j][tx] = s[(size_t)(by + ty + j) * 1024 + bx + tx];
  __syncthreads();
#pragma unroll
  for (int j = 0; j < 32; j += 8)
    d[(size_t)(bx + ty + j) * 1024 + by + tx] = f2b(tile[tx][ty + j]);
}

// ---------- GEMM: C[M,N] = A[M,K=1024] * Bt[N,K=1024]^T, 128x128 tile, BK=32 ----------
// LDS layout: [row][k] as 128 rows x 32 bf16 (64B rows), XOR-swizzled 16B chunks:
//   phys_chunk(r,g) = g ^ ((r>>1)&3). Staged linearly via global_load_lds with
//   inverse-swizzled GLOBAL source (G21: both-sides-or-neither).
__device__ __forceinline__ void stage2(const u16* __restrict__ g, int row0, int k0,
                                       u16* lds, int t) {
#pragma unroll
  for (int j = 0; j < 2; ++j) {
    const int slot = j * 256 + t;                  // 16B slot index in 8KB tile
    const int r = slot >> 2;                       // tile row
    const int gl = (slot & 3) ^ ((r >> 1) & 3);    // logical k-chunk for this phys slot
    const u16* src = g + (((size_t)(row0 + r)) << 10) + (k0 + (gl << 3));
    u16* dst = lds + ((j * 256 + (t & 192)) << 3); // wave-uniform base; HW adds lane*16B
    __builtin_amdgcn_global_load_lds((const __attribute__((address_space(1))) void*)src,
                                     (__attribute__((address_space(3))) void*)dst,
                                     16, 0, 0);
  }
}

template <bool OUT_BF16>
__device__ __forceinline__ void gemm128(const u16* __restrict__ A, const u16* __restrict__ Bt,
                                        const float* __restrict__ bias, int m0, int n0,
                                        float scale, void* outp) {
  __shared__ alignas(16) u16 As[128 * 32];
  __shared__ alignas(16) u16 Bs[128 * 32];
  const int t = threadIdx.x;
  const int lane = t & 63, w = t >> 6;
  const int wr = (w >> 1) * 64, wc = (w & 1) * 64;   // wave 64x64 sub-tile
  const int lr = lane & 15, lg = lane >> 4;          // frag row-in-16, k-chunk

  f32x4 acc[4][4] = {};

  for (int k0 = 0; k0 < 1024; k0 += 32) {
    stage2(A, m0, k0, As, t);
    stage2(Bt, n0, k0, Bs, t);
    __syncthreads();

    bf16x8 af[4], bfr[4];
#pragma unroll
    for (int i = 0; i < 4; ++i) {
      const int r = wr + i * 16 + lr;
      af[i] = *reinterpret_cast<const bf16x8*>(&As[(r << 5) + (((lg ^ (r >> 1)) & 3) << 3)]);
    }
#pragma unroll
    for (int i = 0; i < 4; ++i) {
      const int r = wc + i * 16 + lr;
      bfr[i] = *reinterpret_cast<const bf16x8*>(&Bs[(r << 5) + (((lg ^ (r >> 1)) & 3) << 3)]);
    }
#pragma unroll
    for (int mi = 0; mi < 4; ++mi)
#pragma unroll
      for (int ni = 0; ni < 4; ++ni)
        acc[mi][ni] = __builtin_amdgcn_mfma_f32_16x16x32_bf16(af[mi], bfr[ni], acc[mi][ni], 0, 0, 0);
    __syncthreads();
  }

  // epilogue: C/D layout col=lane&15, row=(lane>>4)*4+reg (m89)
  const int cr = (lane >> 4) * 4, cc = lane & 15;
#pragma unroll
  for (int mi = 0; mi < 4; ++mi) {
#pragma unroll
    for (int ni = 0; ni < 4; ++ni) {
      const int gn = n0 + wc + ni * 16 + cc;
      const float bv = bias[gn];
#pragma unroll
      for (int i = 0; i < 4; ++i) {
        const int gm = m0 + wr + mi * 16 + cr + i;
        const float v = (acc[mi][ni][i] + bv) * scale;
        if (OUT_BF16)
          ((u16*)outp)[((size_t)gm << 10) + gn] = f2b(v);
        else
          ((float*)outp)[((size_t)gm << 10) + gn] = v;
      }
    }
  }
}

// fused QKV: grid (64, 24): y = seg*8 + ntile
__global__ __launch_bounds__(256) void gemm_qkv_kernel(
    const u16* __restrict__ XB, const u16* __restrict__ Wq, const u16* __restrict__ Wk,
    const u16* __restrict__ Wv, const float* __restrict__ bq, const float* __restrict__ bk,
    const float* __restrict__ bv, u16* __restrict__ Q, u16* __restrict__ K, u16* __restrict__ V) {
  const int seg = blockIdx.y >> 3, nt = blockIdx.y & 7;
  const u16* B = seg == 0 ? Wq : (seg == 1 ? Wk : Wv);
  const float* bias = seg == 0 ? bq : (seg == 1 ? bk : bv);
  u16* out = seg == 0 ? Q : (seg == 1 ? K : V);
  const float scale = seg == 0 ? 0.125f : 1.0f;   // 1/sqrt(C)=1/8, applied to (xW+b)
  gemm128<true>(XB, B, bias, blockIdx.x * 128, nt * 128, scale, out);
}

__global__ __launch_bounds__(256) void gemm_out_kernel(const u16* __restrict__ AB,
                                                       const u16* __restrict__ Wo,
                                                       const float* __restrict__ bo,
                                                       float* __restrict__ out) {
  gemm128<false>(AB, Wo, bo, blockIdx.x * 128, blockIdx.y * 128, 1.0f, out);
}

// ---------- per-token channel attention: one wave per (token, head), lane = q ----------
// v4: register prefetch of all K/V (16x dwordx4 in flight; fixes v2's
// VGPR_Count=28 load serialization) + the v2-PROVEN ternary causal mask
// (v3's inline-asm cndmask mask produced wrong results -> reverted).
// No max-subtraction (|q*k| << 1, softmax shift-invariant). In-place over Q.
__global__ __launch_bounds__(256) void attn_kernel(u16* __restrict__ Qb,
                                                   const u16* __restrict__ Kb,
                                                   const u16* __restrict__ Vb) {
  const int w = threadIdx.x >> 6, lane = threadIdx.x & 63;
  const int wid = blockIdx.x * 4 + w;                      // token*16 + head
  const size_t base = (size_t)(wid >> 4) * 1024 + (size_t)(wid & 15) * 64;

  const uint4* K4 = reinterpret_cast<const uint4*>(Kb + base);  // 128B-aligned
  const uint4* V4 = reinterpret_cast<const uint4*>(Vb + base);
  uint4 kc[8], vc[8];
#pragma unroll
  for (int c = 0; c < 8; ++c) kc[c] = K4[c];
#pragma unroll
  for (int c = 0; c < 8; ++c) vc[c] = V4[c];

  const float q = b2f(Qb[base + lane]);                    // already scaled by 1/sqrt(C)
#if __has_builtin(__builtin_amdgcn_exp2f)
  const float qs = q * 1.44269504088896340736f;            // fold ln2: exp(qx)=2^(qs*x)
#define ATTN_EXP(KV) __builtin_amdgcn_exp2f(qs * (KV))
#else
#define ATTN_EXP(KV) __expf(q * (KV))
#endif

  // dual accumulator chains (even/odd) for ILP
  float d0 = 0.f, d1 = 0.f, a0 = 0.f, a1 = 0.f;
#pragma unroll
  for (int c = 0; c < 8; ++c) {
    const u32* kw = reinterpret_cast<const u32*>(&kc[c]);
    const u32* vw = reinterpret_cast<const u32*>(&vc[c]);
#pragma unroll
    for (int j = 0; j < 4; ++j) {
      const int k0 = c * 8 + j * 2;
      const float ea = (k0     <= lane) ? ATTN_EXP(b2f_lo(kw[j])) : 0.f;  // causal k<=q
      const float eb = (k0 + 1 <= lane) ? ATTN_EXP(b2f_hi(kw[j])) : 0.f;
      d0 += ea; a0 = fmaf(ea, b2f_lo(vw[j]), a0);
      d1 += eb; a1 = fmaf(eb, b2f_hi(vw[j]), a1);
    }
  }
  Qb[base + lane] = f2b((a0 + a1) / (d0 + d1));
#undef ATTN_EXP
}

// ---------- launch ----------
extern "C" void kernel_launch(void* const* d_in, const int* in_sizes, int n_in,
                              void* d_out, int out_size, void* d_ws, size_t ws_size,
                              hipStream_t stream) {
  const float* x  = (const float*)d_in[0];
  const float* Wq = (const float*)d_in[1];
  const float* bq = (const float*)d_in[2];
  const float* Wk = (const float*)d_in[3];
  const float* bk = (const float*)d_in[4];
  const float* Wv = (const float*)d_in[5];
  const float* bv = (const float*)d_in[6];
  const float* Wo = (const float*)d_in[7];
  const float* bo = (const float*)d_in[8];
  float* out = (float*)d_out;

  char* ws = (char*)d_ws;
  u16* XB  = (u16*)(ws);                          // x bf16            16 MB
  u16* WqB = (u16*)(ws + (16ull << 20));          // Wq^T bf16          2 MB
  u16* WkB = (u16*)(ws + (18ull << 20));
  u16* WvB = (u16*)(ws + (20ull << 20));
  u16* WoB = (u16*)(ws + (22ull << 20));
  u16* Qb  = (u16*)(ws + (24ull << 20));          // Q bf16 (attn out in-place) 16 MB
  u16* Kb  = (u16*)(ws + (40ull << 20));
  u16* Vb  = (u16*)(ws + (56ull << 20));          // total 72 MB

  cvt_kernel<<<8192, 256, 0, stream>>>(x, XB, 2097152);   // 8.39M elems / 4
  transpose4_kernel<<<dim3(32, 32, 4), dim3(32, 8), 0, stream>>>(
      Wq, Wk, Wv, Wo, WqB, WkB, WvB, WoB);

  gemm_qkv_kernel<<<dim3(64, 24), 256, 0, stream>>>(XB, WqB, WkB, WvB, bq, bk, bv, Qb, Kb, Vb);
  attn_kernel<<<32768, 256, 0, stream>>>(Qb, Kb, Vb);
  gemm_out_kernel<<<dim3(64, 8), 256, 0, stream>>>(Qb, WoB, bo, out);
}

// Round 16
// 245.077 us; speedup vs baseline: 1.2795x; 1.2795x over previous
//
#include <hip/hip_runtime.h>
#include <stdint.h>

typedef unsigned short u16;
typedef unsigned int u32;
typedef __bf16 bf16x8 __attribute__((ext_vector_type(8)));
typedef float f32x4 __attribute__((ext_vector_type(4)));

// ---------- small helpers ----------
__device__ __forceinline__ u16 f2b(float f) {
  uint32_t u = __float_as_uint(f);
  u += 0x7FFFu + ((u >> 16) & 1u);   // RNE (inputs are finite/normal)
  return (u16)(u >> 16);
}
__device__ __forceinline__ float b2f(u16 u) {
  return __uint_as_float(((uint32_t)u) << 16);
}
__device__ __forceinline__ float b2f_lo(u32 w) {  // low bf16 of a dword
  return __uint_as_float(w << 16);
}
__device__ __forceinline__ float b2f_hi(u32 w) {  // high bf16 of a dword
  return __uint_as_float(w & 0xffff0000u);
}

// ---------- convert fp32 -> bf16, vectorized ----------
__global__ __launch_bounds__(256) void cvt_kernel(const float* __restrict__ s,
                                                  u16* __restrict__ d, int n4) {
  int i = blockIdx.x * 256 + threadIdx.x;
  if (i >= n4) return;
  float4 v = reinterpret_cast<const float4*>(s)[i];
  ushort4 o;
  o.x = f2b(v.x); o.y = f2b(v.y); o.z = f2b(v.z); o.w = f2b(v.w);
  reinterpret_cast<ushort4*>(d)[i] = o;
}

// ---------- transpose 4x (1024x1024 fp32 -> bf16 [N][K]), z selects matrix ----------
__global__ __launch_bounds__(256) void transpose4_kernel(
    const float* __restrict__ s0, const float* __restrict__ s1,
    const float* __restrict__ s2, const float* __restrict__ s3,
    u16* __restrict__ d0, u16* __restrict__ d1,
    u16* __restrict__ d2, u16* __restrict__ d3) {
  const int z = blockIdx.z;
  const float* s = z == 0 ? s0 : (z == 1 ? s1 : (z == 2 ? s2 : s3));
  u16*        d = z == 0 ? d0 : (z == 1 ? d1 : (z == 2 ? d2 : d3));
  __shared__ float tile[32][33];
  const int tx = threadIdx.x, ty = threadIdx.y;          // (32, 8)
  const int bx = blockIdx.x * 32, by = blockIdx.y * 32;
#pragma unroll
  for (int j = 0; j < 32; j += 8)
    tile[ty + j][tx] = s[(size_t)(by + ty + j) * 1024 + bx + tx];
  __syncthreads();
#pragma unroll
  for (int j = 0; j < 32; j += 8)
    d[(size_t)(bx + ty + j) * 1024 + by + tx] = f2b(tile[tx][ty + j]);
}

// ---------- GEMM: C[M,N] = A[M,K=1024] * Bt[N,K=1024]^T, 128x128 tile, BK=32 ----------
__device__ __forceinline__ void stage2(const u16* __restrict__ g, int row0, int k0,
                                       u16* lds, int t) {
#pragma unroll
  for (int j = 0; j < 2; ++j) {
    const int slot = j * 256 + t;                  // 16B slot index in 8KB tile
    const int r = slot >> 2;                       // tile row
    const int gl = (slot & 3) ^ ((r >> 1) & 3);    // logical k-chunk for this phys slot
    const u16* src = g + (((size_t)(row0 + r)) << 10) + (k0 + (gl << 3));
    u16* dst = lds + ((j * 256 + (t & 192)) << 3); // wave-uniform base; HW adds lane*16B
    __builtin_amdgcn_global_load_lds((const __attribute__((address_space(1))) void*)src,
                                     (__attribute__((address_space(3))) void*)dst,
                                     16, 0, 0);
  }
}

template <bool OUT_BF16>
__device__ __forceinline__ void gemm128(const u16* __restrict__ A, const u16* __restrict__ Bt,
                                        const float* __restrict__ bias, int m0, int n0,
                                        float scale, void* outp) {
  __shared__ alignas(16) u16 As[128 * 32];
  __shared__ alignas(16) u16 Bs[128 * 32];
  const int t = threadIdx.x;
  const int lane = t & 63, w = t >> 6;
  const int wr = (w >> 1) * 64, wc = (w & 1) * 64;   // wave 64x64 sub-tile
  const int lr = lane & 15, lg = lane >> 4;          // frag row-in-16, k-chunk

  f32x4 acc[4][4] = {};

  for (int k0 = 0; k0 < 1024; k0 += 32) {
    stage2(A, m0, k0, As, t);
    stage2(Bt, n0, k0, Bs, t);
    __syncthreads();

    bf16x8 af[4], bfr[4];
#pragma unroll
    for (int i = 0; i < 4; ++i) {
      const int r = wr + i * 16 + lr;
      af[i] = *reinterpret_cast<const bf16x8*>(&As[(r << 5) + (((lg ^ (r >> 1)) & 3) << 3)]);
    }
#pragma unroll
    for (int i = 0; i < 4; ++i) {
      const int r = wc + i * 16 + lr;
      bfr[i] = *reinterpret_cast<const bf16x8*>(&Bs[(r << 5) + (((lg ^ (r >> 1)) & 3) << 3)]);
    }
#pragma unroll
    for (int mi = 0; mi < 4; ++mi)
#pragma unroll
      for (int ni = 0; ni < 4; ++ni)
        acc[mi][ni] = __builtin_amdgcn_mfma_f32_16x16x32_bf16(af[mi], bfr[ni], acc[mi][ni], 0, 0, 0);
    __syncthreads();
  }

  // epilogue: C/D layout col=lane&15, row=(lane>>4)*4+reg (m89)
  const int cr = (lane >> 4) * 4, cc = lane & 15;
#pragma unroll
  for (int mi = 0; mi < 4; ++mi) {
#pragma unroll
    for (int ni = 0; ni < 4; ++ni) {
      const int gn = n0 + wc + ni * 16 + cc;
      const float bv = bias[gn];
#pragma unroll
      for (int i = 0; i < 4; ++i) {
        const int gm = m0 + wr + mi * 16 + cr + i;
        const float v = (acc[mi][ni][i] + bv) * scale;
        if (OUT_BF16)
          ((u16*)outp)[((size_t)gm << 10) + gn] = f2b(v);
        else
          ((float*)outp)[((size_t)gm << 10) + gn] = v;
      }
    }
  }
}

// fused QKV: grid (64, 24): y = seg*8 + ntile
__global__ __launch_bounds__(256) void gemm_qkv_kernel(
    const u16* __restrict__ XB, const u16* __restrict__ Wq, const u16* __restrict__ Wk,
    const u16* __restrict__ Wv, const float* __restrict__ bq, const float* __restrict__ bk,
    const float* __restrict__ bv, u16* __restrict__ Q, u16* __restrict__ K, u16* __restrict__ V) {
  const int seg = blockIdx.y >> 3, nt = blockIdx.y & 7;
  const u16* B = seg == 0 ? Wq : (seg == 1 ? Wk : Wv);
  const float* bias = seg == 0 ? bq : (seg == 1 ? bk : bv);
  u16* out = seg == 0 ? Q : (seg == 1 ? K : V);
  const float scale = seg == 0 ? 0.125f : 1.0f;   // 1/sqrt(C)=1/8, applied to (xW+b)
  gemm128<true>(XB, B, bias, blockIdx.x * 128, nt * 128, scale, out);
}

__global__ __launch_bounds__(256) void gemm_out_kernel(const u16* __restrict__ AB,
                                                       const u16* __restrict__ Wo,
                                                       const float* __restrict__ bo,
                                                       float* __restrict__ out) {
  gemm128<false>(AB, Wo, bo, blockIdx.x * 128, blockIdx.y * 128, 1.0f, out);
}

// ---------- per-token channel attention v5: lane = (token,head), triangular ----------
// Restructure vs v4 (142us, VALU-issue-bound): each THREAD owns one (token,head)
// problem; the q-loop is wave-uniform so the k-loop runs exactly q+1 iterations
// -> triangular work (51% of square), ZERO per-element masking (was cmp+cndmask
// per elem). K/V staged in LDS as [256][33]-dword rows (stride 33 -> bank
// (t+c)%32, 2 lanes/bank = conflict-free). q processed in chunks of 8 (static
// sub-index -> Q row as uint4 loads, outputs packed to uint4 stores); each
// even/odd q-pair shares one k-loop (halves ds_reads). In-place over Q.
__global__ __launch_bounds__(256) void attn_kernel(u16* __restrict__ Qb,
                                                   const u16* __restrict__ Kb,
                                                   const u16* __restrict__ Vb) {
  __shared__ u32 Ks[256 * 33];
  __shared__ u32 Vs[256 * 33];
  const int tid = threadIdx.x;
  const int th0 = blockIdx.x * 256;                      // first tokenhead of block

  // stage K,V: 8192 dwords each, uint4 global loads, b32 LDS writes
  const uint4* Kg4 = reinterpret_cast<const uint4*>(Kb + (size_t)th0 * 64);
  const uint4* Vg4 = reinterpret_cast<const uint4*>(Vb + (size_t)th0 * 64);
#pragma unroll
  for (int i0 = 0; i0 < 2048; i0 += 256) {
    const int i = i0 + tid;
    const int t = i >> 3, c = (i & 7) * 4;
    u32* pk = &Ks[t * 33 + c];
    u32* pv = &Vs[t * 33 + c];
    uint4 kk = Kg4[i];
    uint4 vv = Vg4[i];
    pk[0] = kk.x; pk[1] = kk.y; pk[2] = kk.z; pk[3] = kk.w;
    pv[0] = vv.x; pv[1] = vv.y; pv[2] = vv.z; pv[3] = vv.w;
  }
  __syncthreads();

  const int b33 = tid * 33;
  const size_t qbase = (size_t)(th0 + tid) * 64;         // u16 index of lane's row

#if __has_builtin(__builtin_amdgcn_exp2f)
#define QSCL 1.44269504088896340736f
#define ATTN_EXP(S, KV) __builtin_amdgcn_exp2f((S) * (KV))
#else
#define QSCL 1.0f
#define ATTN_EXP(S, KV) __expf((S) * (KV))
#endif

  for (int qc = 0; qc < 8; ++qc) {
    uint4 qv4 = *reinterpret_cast<const uint4*>(Qb + qbase + qc * 8);
    const u32* qw = reinterpret_cast<const u32*>(&qv4);
    u32 oo[4];
#pragma unroll
    for (int j2 = 0; j2 < 4; ++j2) {
      // rows q_even = qc*8 + 2*j2 (even) and q_odd = q_even+1 (odd)
      const int fe = qc * 4 + j2;                        // full shared pairs
      const float qse = b2f_lo(qw[j2]) * QSCL;
      const float qso = b2f_hi(qw[j2]) * QSCL;
      float de0 = 0.f, de1 = 0.f, ae0 = 0.f, ae1 = 0.f;
      float do0 = 0.f, do1 = 0.f, ao0 = 0.f, ao1 = 0.f;
      int c = 0;
      for (; c + 2 <= fe; c += 2) {                      // unroll-by-2, 4 ds_reads up front
        const u32 kwa = Ks[b33 + c],     vwa = Vs[b33 + c];
        const u32 kwb = Ks[b33 + c + 1], vwb = Vs[b33 + c + 1];
        {
          const float k0 = b2f_lo(kwa), k1 = b2f_hi(kwa);
          const float v0 = b2f_lo(vwa), v1 = b2f_hi(vwa);
          const float ee0 = ATTN_EXP(qse, k0), ee1 = ATTN_EXP(qse, k1);
          const float eo0 = ATTN_EXP(qso, k0), eo1 = ATTN_EXP(qso, k1);
          de0 += ee0; ae0 = fmaf(ee0, v0, ae0);
          de1 += ee1; ae1 = fmaf(ee1, v1, ae1);
          do0 += eo0; ao0 = fmaf(eo0, v0, ao0);
          do1 += eo1; ao1 = fmaf(eo1, v1, ao1);
        }
        {
          const float k0 = b2f_lo(kwb), k1 = b2f_hi(kwb);
          const float v0 = b2f_lo(vwb), v1 = b2f_hi(vwb);
          const float ee0 = ATTN_EXP(qse, k0), ee1 = ATTN_EXP(qse, k1);
          const float eo0 = ATTN_EXP(qso, k0), eo1 = ATTN_EXP(qso, k1);
          de0 += ee0; ae0 = fmaf(ee0, v0, ae0);
          de1 += ee1; ae1 = fmaf(ee1, v1, ae1);
          do0 += eo0; ao0 = fmaf(eo0, v0, ao0);
          do1 += eo1; ao1 = fmaf(eo1, v1, ao1);
        }
      }
      if (c < fe) {                                      // leftover full pair
        const u32 kwa = Ks[b33 + c], vwa = Vs[b33 + c];
        const float k0 = b2f_lo(kwa), k1 = b2f_hi(kwa);
        const float v0 = b2f_lo(vwa), v1 = b2f_hi(vwa);
        const float ee0 = ATTN_EXP(qse, k0), ee1 = ATTN_EXP(qse, k1);
        const float eo0 = ATTN_EXP(qso, k0), eo1 = ATTN_EXP(qso, k1);
        de0 += ee0; ae0 = fmaf(ee0, v0, ae0);
        de1 += ee1; ae1 = fmaf(ee1, v1, ae1);
        do0 += eo0; ao0 = fmaf(eo0, v0, ao0);
        do1 += eo1; ao1 = fmaf(eo1, v1, ao1);
      }
      {                                                  // boundary chunk c = fe:
        const u32 kwa = Ks[b33 + fe], vwa = Vs[b33 + fe];
        const float k0 = b2f_lo(kwa), k1 = b2f_hi(kwa);
        const float v0 = b2f_lo(vwa), v1 = b2f_hi(vwa);
        const float ee0 = ATTN_EXP(qse, k0);             // even row: k = q_even only
        de0 += ee0; ae0 = fmaf(ee0, v0, ae0);
        const float eo0 = ATTN_EXP(qso, k0), eo1 = ATTN_EXP(qso, k1);  // odd row: both
        do0 += eo0; ao0 = fmaf(eo0, v0, ao0);
        do1 += eo1; ao1 = fmaf(eo1, v1, ao1);
      }
      const float oe = (ae0 + ae1) / (de0 + de1);
      const float od = (ao0 + ao1) / (do0 + do1);
      oo[j2] = (u32)f2b(oe) | ((u32)f2b(od) << 16);
    }
    *reinterpret_cast<uint4*>(Qb + qbase + qc * 8) = *reinterpret_cast<uint4*>(oo);
  }
#undef ATTN_EXP
#undef QSCL
}

// ---------- launch ----------
extern "C" void kernel_launch(void* const* d_in, const int* in_sizes, int n_in,
                              void* d_out, int out_size, void* d_ws, size_t ws_size,
                              hipStream_t stream) {
  const float* x  = (const float*)d_in[0];
  const float* Wq = (const float*)d_in[1];
  const float* bq = (const float*)d_in[2];
  const float* Wk = (const float*)d_in[3];
  const float* bk = (const float*)d_in[4];
  const float* Wv = (const float*)d_in[5];
  const float* bv = (const float*)d_in[6];
  const float* Wo = (const float*)d_in[7];
  const float* bo = (const float*)d_in[8];
  float* out = (float*)d_out;

  char* ws = (char*)d_ws;
  u16* XB  = (u16*)(ws);                          // x bf16            16 MB
  u16* WqB = (u16*)(ws + (16ull << 20));          // Wq^T bf16          2 MB
  u16* WkB = (u16*)(ws + (18ull << 20));
  u16* WvB = (u16*)(ws + (20ull << 20));
  u16* WoB = (u16*)(ws + (22ull << 20));
  u16* Qb  = (u16*)(ws + (24ull << 20));          // Q bf16 (attn out in-place) 16 MB
  u16* Kb  = (u16*)(ws + (40ull << 20));
  u16* Vb  = (u16*)(ws + (56ull << 20));          // total 72 MB

  cvt_kernel<<<8192, 256, 0, stream>>>(x, XB, 2097152);   // 8.39M elems / 4
  transpose4_kernel<<<dim3(32, 32, 4), dim3(32, 8), 0, stream>>>(
      Wq, Wk, Wv, Wo, WqB, WkB, WvB, WoB);

  gemm_qkv_kernel<<<dim3(64, 24), 256, 0, stream>>>(XB, WqB, WkB, WvB, bq, bk, bv, Qb, Kb, Vb);
  attn_kernel<<<512, 256, 0, stream>>>(Qb, Kb, Vb);
  gemm_out_kernel<<<dim3(64, 8), 256, 0, stream>>>(Qb, WoB, bo, out);
}